// Round 5
// baseline (174.516 us; speedup 1.0000x reference)
//
#include <hip/hip_runtime.h>
#include <hip/hip_bf16.h>

#define B_ 1024
#define P_ 8
#define D_ 2048
#define FD_ (P_ * D_)   // 16384
#define NID 64
#define MARGIN_ 0.3f
#define EPS_ 1e-12f

typedef unsigned short u16;
typedef float float4_t __attribute__((ext_vector_type(4)));

#define AS1 __attribute__((address_space(1)))
#define AS3 __attribute__((address_space(3)))

__device__ __forceinline__ float bf2f(unsigned v) {
    unsigned x = v << 16;
    float f;
    __builtin_memcpy(&f, &x, 4);
    return f;
}

// ---------------- workspace layout (bytes) ----------------
static const size_t OFF_COUNTS = 0;         // 64 fp32
static const size_t OFF_OFFS   = 256;       // 64 int
static const size_t OFF_PERM   = 512;       // 1024 int -> ends 4608
static const size_t OFF_NEG    = 4608;
static const size_t OFF_POS    = 8176;      // adjacent to S so one memset covers both
static const size_t OFF_S      = 8192;      // 1024*8 fp32 = 32 KB -> 40960
static const size_t OFF_SQ     = 40960;     // 1024*8 fp32
static const size_t OFF_DAP    = 73728;     // 1024 fp32
static const size_t OFF_FB     = 131072;    // PLANE-MAJOR fp8: [p][i][d], 16 MB
static const size_t OFF_PD     = OFF_FB + (size_t)B_ * FD_;  // 8 planes * 1024*1024 bf16 = 16 MB

// ---------------- kernel 1: histogram counts + prefix + perm + negcnt ----------------
__global__ void k_counts(const int* __restrict__ labels, float* countsf, int* offs,
                         int* perm, float* negcnt) {
    __shared__ int h[NID], o[NID], cur[NID];
    int tid = threadIdx.x;
    if (tid < NID) h[tid] = 0;
    __syncthreads();
    for (int i = tid; i < B_; i += 256) atomicAdd(&h[labels[i]], 1);
    __syncthreads();
    if (tid == 0) {
        int acc = 0;
        long long ss = 0;
        for (int c = 0; c < NID; c++) {
            o[c] = acc;
            acc += h[c];
            ss += (long long)h[c] * h[c];
        }
        *negcnt = (float)((long long)B_ * B_ - ss);
    }
    __syncthreads();
    if (tid < NID) {
        countsf[tid] = (float)h[tid];
        offs[tid] = o[tid];
        cur[tid] = o[tid];
    }
    __syncthreads();
    for (int i = tid; i < B_; i += 256) {
        int pos = atomicAdd(&cur[labels[i]], 1);
        perm[pos] = i;
    }
}

// ---------------- kernel 2: fp8 cast (plane-major) + sq; wave-per-plane ----------------
__global__ void k_rowstats(const float* __restrict__ feats, unsigned char* __restrict__ fb,
                           float* __restrict__ sq) {
    int i = blockIdx.x;
    int tid = threadIdx.x;
    int p = tid >> 6, lane = tid & 63;  // 8 waves, wave = plane
    const float* frow = feats + (size_t)i * FD_ + p * D_;
    unsigned char* brow = fb + (size_t)p * B_ * D_ + (size_t)i * D_;
    float s2 = 0.f;
#pragma unroll
    for (int ch = 0; ch < 8; ch++) {
        int d = ch * 256 + lane * 4;
        float4 f = *(const float4*)(frow + d);
        int pk = __builtin_amdgcn_cvt_pk_fp8_f32(f.x, f.y, 0, false);
        pk = __builtin_amdgcn_cvt_pk_fp8_f32(f.z, f.w, pk, true);
        *(unsigned int*)(brow + d) = (unsigned int)pk;
        s2 += f.x * f.x + f.y * f.y + f.z * f.z + f.w * f.w;
    }
    for (int o = 32; o; o >>= 1) s2 += __shfl_down(s2, o, 64);
    if (lane == 0) sq[i * P_ + p] = s2;
}

// ---------------- kernel 3: fp8 MFMA pair kernel ----------------
// grid (8,8,8) with p = blockIdx.x (XCD = id%8 -> one plane per XCD, L2-resident
// 2 MB fb slice + 2 MB pd slice). j = blockIdx.y*128, i = blockIdx.z*128.
// block 256 = 4 spatial waves (2x2 of 64x64), full K=2048 per wave, 16 kb iters.
// Staging: global_load_lds width=16, XOR 16-B-chunk swizzle (phys = logical ^ (row&7)).
// LDS ~34 KB -> 4 blocks/CU (4 independent barrier groups).
__global__ __launch_bounds__(256, 4) void k_pairs(const unsigned char* __restrict__ fb,
                                                  const float* __restrict__ sq,
                                                  const int* __restrict__ labels,
                                                  float* __restrict__ S,
                                                  u16* __restrict__ pd) {
    const int p  = blockIdx.x;
    const int j0 = blockIdx.y * 128;
    const int i0 = blockIdx.z * 128;
    __shared__ __align__(16) unsigned char As[16384];
    __shared__ __align__(16) unsigned char Bs[16384];
    __shared__ float sqAs[128], sqBs[128];
    __shared__ int labA[128], labB[128];
    const int tid = threadIdx.x;
    const int lane = tid & 63, wid = tid >> 6;
    if (tid < 128) {
        sqAs[tid] = sq[(i0 + tid) * 8 + p];
        labA[tid] = labels[i0 + tid];
    } else {
        int t = tid - 128;
        sqBs[t] = sq[(j0 + t) * 8 + p];
        labB[t] = labels[j0 + t];
    }

    const int wi = (wid >> 1) * 64, wj = (wid & 1) * 64;
    const int lhi = lane >> 4, llo = lane & 15;
    const int sl = llo & 7;
    const int lr = lane >> 3;          // staging: lane -> row (L>>3)
    const int lc = (lane & 7) ^ lr;    // physical chunk L&7 holds logical (L&7)^(L>>3)

    const size_t plbase = (size_t)p * ((size_t)B_ * D_);
    const unsigned char* gA[4];
    const unsigned char* gB[4];
    unsigned char* lA[4];
    unsigned char* lB[4];
#pragma unroll
    for (int inst = 0; inst < 4; inst++) {
        int r0 = wid * 32 + inst * 8;  // 4 waves x 4 insts x 8 rows = 128 rows
        gA[inst] = fb + plbase + (size_t)(i0 + r0 + lr) * D_ + lc * 16;
        gB[inst] = fb + plbase + (size_t)(j0 + r0 + lr) * D_ + lc * 16;
        lA[inst] = As + r0 * 128;  // wave-uniform base; HW adds lane*16B
        lB[inst] = Bs + r0 * 128;
    }

    float4_t acc[4][4];
#pragma unroll
    for (int a = 0; a < 4; a++)
#pragma unroll
        for (int b = 0; b < 4; b++) acc[a][b] = (float4_t){0.f, 0.f, 0.f, 0.f};

    for (int kb = 0; kb < 16; kb++) {
        const int koff = kb * 128;
        __syncthreads();  // previous iter's ds_reads done
#pragma unroll
        for (int inst = 0; inst < 4; inst++) {
            __builtin_amdgcn_global_load_lds((const AS1 void*)(gA[inst] + koff),
                                             (AS3 void*)lA[inst], 16, 0, 0);
            __builtin_amdgcn_global_load_lds((const AS1 void*)(gB[inst] + koff),
                                             (AS3 void*)lB[inst], 16, 0, 0);
        }
        __syncthreads();  // staging complete
#pragma unroll
        for (int ks = 0; ks < 4; ks++) {
            // lane quad lhi needs bytes [ks*32 + lhi*8, +8): logical chunk 2ks+(lhi>>1),
            // sub-offset (lhi&1)*8; physical chunk = logical ^ (row&7)
            const int pcb = ((2 * ks + (lhi >> 1)) ^ sl) * 16 + (lhi & 1) * 8;
            long af[4], bf[4];
#pragma unroll
            for (int a = 0; a < 4; a++) {
                af[a] = *(const long*)(As + (wi + a * 16 + llo) * 128 + pcb);
                bf[a] = *(const long*)(Bs + (wj + a * 16 + llo) * 128 + pcb);
            }
#pragma unroll
            for (int a = 0; a < 4; a++)
#pragma unroll
                for (int b = 0; b < 4; b++)
                    acc[a][b] = __builtin_amdgcn_mfma_f32_16x16x32_fp8_fp8(
                        af[a], bf[b], acc[a][b], 0, 0, 0);
        }
    }
    // ---- epilogue: sqrt -> pd plane; label-masked row sums -> S ----
    // C/D layout: col = lane&15, row = (lane>>4)*4 + reg
    u16* outp = pd + (size_t)p * B_ * B_;
    float rs[4][4];
#pragma unroll
    for (int a = 0; a < 4; a++)
#pragma unroll
        for (int r = 0; r < 4; r++) rs[a][r] = 0.f;
#pragma unroll
    for (int a = 0; a < 4; a++) {
        int la0 = labA[wi + a * 16 + lhi * 4 + 0];
        int la1 = labA[wi + a * 16 + lhi * 4 + 1];
        int la2 = labA[wi + a * 16 + lhi * 4 + 2];
        int la3 = labA[wi + a * 16 + lhi * 4 + 3];
#pragma unroll
        for (int b = 0; b < 4; b++) {
            int jl = wj + b * 16 + llo;
            int lb = labB[jl];
#pragma unroll
            for (int r = 0; r < 4; r++) {
                int il = wi + a * 16 + lhi * 4 + r;
                float t = acc[a][b][r];
                float d2 = sqAs[il] + sqBs[jl] - 2.0f * t;
                outp[(size_t)(i0 + il) * B_ + (j0 + jl)] =
                    __bfloat16_as_ushort(__float2bfloat16(sqrtf(fmaxf(d2, EPS_))));
                int la = (r == 0) ? la0 : (r == 1) ? la1 : (r == 2) ? la2 : la3;
                if (lb == la) rs[a][r] += t;
            }
        }
    }
#pragma unroll
    for (int a = 0; a < 4; a++)
#pragma unroll
        for (int r = 0; r < 4; r++) {
            float v = rs[a][r];
            v += __shfl_xor(v, 1, 64);
            v += __shfl_xor(v, 2, 64);
            v += __shfl_xor(v, 4, 64);
            v += __shfl_xor(v, 8, 64);
            if (llo == 0)
                atomicAdd(&S[(size_t)(i0 + wi + a * 16 + lhi * 4 + r) * 8 + p], v);
        }
}

// ---------------- kernel 4: d_ap from Gram row sums ----------------
__global__ void k_dap(const float* __restrict__ S, const float* __restrict__ sq,
                      const float* __restrict__ countsf, const int* __restrict__ offs,
                      const int* __restrict__ perm, float* __restrict__ dap) {
    int c = blockIdx.x;
    int tid = threadIdx.x;
    int cnt = (int)countsf[c];
    int off = offs[c];
    __shared__ float T[8];
    if (tid < 8) {
        float t = 0.f;
        for (int m = 0; m < cnt; m++) t += S[(size_t)perm[off + m] * 8 + tid];
        T[tid] = t;
    }
    __syncthreads();
    float n = fmaxf((float)cnt, 1.f);
    float inv = 1.f / n, inv2 = inv * inv;
    for (int m = tid; m < cnt; m += 64) {
        int i = perm[off + m];
        float d = 0.f;
#pragma unroll
        for (int p = 0; p < 8; p++) {
            float d2 = sq[i * 8 + p] - 2.f * inv * S[(size_t)i * 8 + p] + inv2 * T[p];
            d += sqrtf(fmaxf(d2, EPS_));
        }
        dap[i] = d;
    }
}

// ---------------- kernel 5: masked margin reduction, single pass ----------------
__global__ void k_lossred(const u16* __restrict__ pd, const float* __restrict__ dap,
                          const int* __restrict__ labels, float* possum) {
    int i = blockIdx.x;
    int tid = threadIdx.x;
    float di = dap[i];
    int li = labels[i];
    int jb = tid * 4;  // 256 threads x 4 j = 1024
    float daa0 = 0.f, daa1 = 0.f, daa2 = 0.f, daa3 = 0.f;
#pragma unroll
    for (int p = 0; p < 8; p++) {
        uint2 v = *(const uint2*)&pd[((size_t)p << 20) + (size_t)i * B_ + jb];
        daa0 += bf2f(v.x & 0xFFFFu);
        daa1 += bf2f(v.x >> 16);
        daa2 += bf2f(v.y & 0xFFFFu);
        daa3 += bf2f(v.y >> 16);
    }
    float lsum = 0.f;
    float daas[4] = {daa0, daa1, daa2, daa3};
#pragma unroll
    for (int q = 0; q < 4; q++) {
        int j = jb + q;
        if (labels[j] != li) lsum += fmaxf(di + dap[j] - daas[q] + MARGIN_, 0.f);
    }
    for (int o = 32; o; o >>= 1) lsum += __shfl_down(lsum, o, 64);
    __shared__ float red[4];
    int wid = tid >> 6, lane = tid & 63;
    if (lane == 0) red[wid] = lsum;
    __syncthreads();
    if (tid == 0) atomicAdd(possum, red[0] + red[1] + red[2] + red[3]);
}

__global__ void k_finalize(const float* possum, const float* negcnt, float* out) {
    out[0] = possum[0] / negcnt[0];
}

// ---------------- launch ----------------
extern "C" void kernel_launch(void* const* d_in, const int* in_sizes, int n_in,
                              void* d_out, int out_size, void* d_ws, size_t ws_size,
                              hipStream_t stream) {
    const float* feats = (const float*)d_in[0];
    const int* labels  = (const int*)d_in[1];
    float* out = (float*)d_out;

    char* w = (char*)d_ws;
    float* countsf = (float*)(w + OFF_COUNTS);
    int* offs      = (int*)(w + OFF_OFFS);
    int* perm      = (int*)(w + OFF_PERM);
    float* negcnt  = (float*)(w + OFF_NEG);
    float* possum  = (float*)(w + OFF_POS);
    float* S       = (float*)(w + OFF_S);
    float* sq      = (float*)(w + OFF_SQ);
    float* dap     = (float*)(w + OFF_DAP);
    unsigned char* fb = (unsigned char*)(w + OFF_FB);
    u16* pd        = (u16*)(w + OFF_PD);

    // zero possum (at OFF_POS) and S (at OFF_S) in one memset
    hipMemsetAsync(w + OFF_POS, 0, (OFF_S - OFF_POS) + (size_t)B_ * P_ * 4, stream);

    k_counts<<<1, 256, 0, stream>>>(labels, countsf, offs, perm, negcnt);
    k_rowstats<<<B_, 512, 0, stream>>>(feats, fb, sq);
    k_pairs<<<dim3(8, 8, 8), 256, 0, stream>>>(fb, sq, labels, S, pd);
    k_dap<<<NID, 64, 0, stream>>>(S, sq, countsf, offs, perm, dap);
    k_lossred<<<B_, 256, 0, stream>>>(pd, dap, labels, possum);
    k_finalize<<<1, 1, 0, stream>>>(possum, negcnt, out);
}